// Round 5
// baseline (96.123 us; speedup 1.0000x reference)
//
#include <hip/hip_runtime.h>
#include <math.h>

#define B 1024
#define E 256
#define H 4
#define DH 64
#define L 192
#define NF 16384
#define NO 49152

// ---------------------------------------------------------------------------
// Kernel 1: q = scene@Wq^T+bq ; Y[b,h,:] = q_h @ Wk_h ; sb[b,h] = q_h·bk_h.
// 4 batches per block, 256 blocks. Also computes per-batch start offsets
// (binary search over the sorted batch arrays) for the batches it owns.
// ---------------------------------------------------------------------------
__global__ __launch_bounds__(256) void qy_kernel(
    const float* __restrict__ scene,
    const float* __restrict__ ipw, const float* __restrict__ ipb,
    const int* __restrict__ fb, const int* __restrict__ ob,
    int* __restrict__ start_f, int* __restrict__ start_o,
    float* __restrict__ Yws, float* __restrict__ sbws)
{
  int b0 = blockIdx.x * 4;
  int t = threadIdx.x;

  // ---- starts: threads 0..4 cover b0..b0+4 (overlap with next block benign)
  if (t <= 4) {
    int b = b0 + t;
    if (b <= B) {
      int lo = 0, hi = NF;
      while (lo < hi) { int m = (lo + hi) >> 1; if (fb[m] < b) lo = m + 1; else hi = m; }
      start_f[b] = lo;
      lo = 0; hi = NO;
      while (lo < hi) { int m = (lo + hi) >> 1; if (ob[m] < b) lo = m + 1; else hi = m; }
      start_o[b] = lo;
    }
  }

  __shared__ float sc_s[4][E];
  __shared__ float q_s[4][E];

  for (int i = t; i < 4 * E; i += 256)
    ((float*)sc_s)[i] = scene[(size_t)b0 * E + i];
  __syncthreads();

  // q[b][t] for b=0..3 (Wq row t per thread; L2-hot)
  {
    const float* wrow = ipw + (size_t)t * E;
    float a0 = ipb[t], a1 = a0, a2 = a0, a3 = a0;
#pragma unroll 8
    for (int j = 0; j < E; j += 4) {
      float4 w4 = *(const float4*)(wrow + j);
      a0 += sc_s[0][j]*w4.x + sc_s[0][j+1]*w4.y + sc_s[0][j+2]*w4.z + sc_s[0][j+3]*w4.w;
      a1 += sc_s[1][j]*w4.x + sc_s[1][j+1]*w4.y + sc_s[1][j+2]*w4.z + sc_s[1][j+3]*w4.w;
      a2 += sc_s[2][j]*w4.x + sc_s[2][j+1]*w4.y + sc_s[2][j+2]*w4.z + sc_s[2][j+3]*w4.w;
      a3 += sc_s[3][j]*w4.x + sc_s[3][j+1]*w4.y + sc_s[3][j+2]*w4.z + sc_s[3][j+3]*w4.w;
    }
    q_s[0][t] = a0; q_s[1][t] = a1; q_s[2][t] = a2; q_s[3][t] = a3;
  }
  __syncthreads();

  // sb[b][h] = q_h · bk_h
  if (t < 16) {
    int b = t >> 2, h = t & 3;
    float acc = 0.f;
#pragma unroll 8
    for (int d = 0; d < DH; ++d)
      acc += q_s[b][h * DH + d] * ipb[E + h * DH + d];
    sbws[(size_t)(b0 + b) * H + h] = acc;
  }

  // Y[b][h][e=t] = sum_d q[b][h*64+d] * Wk[h*64+d][e]  (coalesced over t)
  {
    const float* Wk = ipw + (size_t)E * E;
    float acc[4][4] = {};
#pragma unroll
    for (int h = 0; h < H; ++h) {
#pragma unroll 4
      for (int d = 0; d < DH; ++d) {
        float w = Wk[(size_t)(h * DH + d) * E + t];
#pragma unroll
        for (int b = 0; b < 4; ++b)
          acc[b][h] += q_s[b][h * DH + d] * w;
      }
    }
#pragma unroll
    for (int b = 0; b < 4; ++b)
#pragma unroll
      for (int h = 0; h < H; ++h)
        Yws[(size_t)(b0 + b) * (H * E) + h * E + t] = acc[b][h];
  }
}

// ---------------------------------------------------------------------------
// Kernel 2: single-pass X-stream with online softmax (flash-style).
// One block (4 waves) per batch; wave w owns rows s = w, w+4, ...
// Per row: 16B/lane coalesced load; per-lane Y slice hoisted to registers;
// 4-head scores via 6-level butterfly; online (m, sum, Zacc) update.
// Partials merged across waves at the end. X read exactly ONCE.
// ---------------------------------------------------------------------------
__global__ __launch_bounds__(256) void stream_kernel(
    const float* __restrict__ face, const float* __restrict__ obj,
    const float* __restrict__ Yws, const float* __restrict__ sbws,
    const int* __restrict__ start_f, const int* __restrict__ start_o,
    float* __restrict__ Zws, float* __restrict__ attnw)
{
  int b = blockIdx.x, t = threadIdx.x;
  int wave = t >> 6, lane = t & 63;

  __shared__ float Y_s[H][E];           // 4 KB
  __shared__ float s_s[H][L];           // 3 KB raw scores
  __shared__ float Zp_s[4][H][E];       // 16 KB per-wave Z partials
  __shared__ float mw_s[4][H], sumw_s[4][H];
  __shared__ float sb_s[H];

  int sf0 = start_f[b], cf = start_f[b + 1] - sf0;
  int so0 = start_o[b], co = start_o[b + 1] - so0;
  int n_f = min(cf, L);
  int n   = min(cf + co, L);

  if (n == 0) {
    if (t < L) attnw[(size_t)b * L + t] = 1.0f / L;
#pragma unroll
    for (int h = 0; h < H; ++h)
      Zws[(size_t)b * (H * E) + h * E + t] = 0.f;
    return;
  }

  for (int i = t; i < H * E; i += 256)
    ((float*)Y_s)[i] = Yws[(size_t)b * (H * E) + i];
  if (t < H) sb_s[t] = sbws[(size_t)b * H + t];
  __syncthreads();

  // hoist per-lane Y slices (loop-invariant across rows)
  float4 y0 = *(const float4*)&Y_s[0][4 * lane];
  float4 y1 = *(const float4*)&Y_s[1][4 * lane];
  float4 y2 = *(const float4*)&Y_s[2][4 * lane];
  float4 y3 = *(const float4*)&Y_s[3][4 * lane];
  float sb0 = sb_s[0], sb1 = sb_s[1], sb2 = sb_s[2], sb3 = sb_s[3];

  float m0 = -3.0e38f, m1 = -3.0e38f, m2 = -3.0e38f, m3 = -3.0e38f;
  float u0 = 0.f, u1 = 0.f, u2 = 0.f, u3 = 0.f;          // running exp-sums
  float4 acc0 = {0,0,0,0}, acc1 = {0,0,0,0}, acc2 = {0,0,0,0}, acc3 = {0,0,0,0};

  for (int s = wave; s < n; s += 4) {
    const float* xrow = (s < n_f) ? face + (size_t)(sf0 + s) * E
                                  : obj  + (size_t)(so0 + s - n_f) * E;
    float4 x4 = ((const float4*)xrow)[lane];

    float p0 = x4.x*y0.x + x4.y*y0.y + x4.z*y0.z + x4.w*y0.w;
    float p1 = x4.x*y1.x + x4.y*y1.y + x4.z*y1.z + x4.w*y1.w;
    float p2 = x4.x*y2.x + x4.y*y2.y + x4.z*y2.z + x4.w*y2.w;
    float p3 = x4.x*y3.x + x4.y*y3.y + x4.z*y3.z + x4.w*y3.w;
#pragma unroll
    for (int o = 32; o; o >>= 1) {
      p0 += __shfl_xor(p0, o); p1 += __shfl_xor(p1, o);
      p2 += __shfl_xor(p2, o); p3 += __shfl_xor(p3, o);
    }
    p0 = (p0 + sb0) * 0.125f;
    p1 = (p1 + sb1) * 0.125f;
    p2 = (p2 + sb2) * 0.125f;
    p3 = (p3 + sb3) * 0.125f;
    if (lane == 0) {
      s_s[0][s] = p0; s_s[1][s] = p1; s_s[2][s] = p2; s_s[3][s] = p3;
    }
    // online update (branches are wave-uniform: p,m uniform across lanes)
    if (p0 > m0) {
      float f = __expf(m0 - p0);
      acc0.x = acc0.x*f + x4.x; acc0.y = acc0.y*f + x4.y;
      acc0.z = acc0.z*f + x4.z; acc0.w = acc0.w*f + x4.w;
      u0 = u0*f + 1.f; m0 = p0;
    } else {
      float e = __expf(p0 - m0);
      acc0.x += e*x4.x; acc0.y += e*x4.y; acc0.z += e*x4.z; acc0.w += e*x4.w;
      u0 += e;
    }
    if (p1 > m1) {
      float f = __expf(m1 - p1);
      acc1.x = acc1.x*f + x4.x; acc1.y = acc1.y*f + x4.y;
      acc1.z = acc1.z*f + x4.z; acc1.w = acc1.w*f + x4.w;
      u1 = u1*f + 1.f; m1 = p1;
    } else {
      float e = __expf(p1 - m1);
      acc1.x += e*x4.x; acc1.y += e*x4.y; acc1.z += e*x4.z; acc1.w += e*x4.w;
      u1 += e;
    }
    if (p2 > m2) {
      float f = __expf(m2 - p2);
      acc2.x = acc2.x*f + x4.x; acc2.y = acc2.y*f + x4.y;
      acc2.z = acc2.z*f + x4.z; acc2.w = acc2.w*f + x4.w;
      u2 = u2*f + 1.f; m2 = p2;
    } else {
      float e = __expf(p2 - m2);
      acc2.x += e*x4.x; acc2.y += e*x4.y; acc2.z += e*x4.z; acc2.w += e*x4.w;
      u2 += e;
    }
    if (p3 > m3) {
      float f = __expf(m3 - p3);
      acc3.x = acc3.x*f + x4.x; acc3.y = acc3.y*f + x4.y;
      acc3.z = acc3.z*f + x4.z; acc3.w = acc3.w*f + x4.w;
      u3 = u3*f + 1.f; m3 = p3;
    } else {
      float e = __expf(p3 - m3);
      acc3.x += e*x4.x; acc3.y += e*x4.y; acc3.z += e*x4.z; acc3.w += e*x4.w;
      u3 += e;
    }
  }

  // store per-wave partials
  *(float4*)&Zp_s[wave][0][4 * lane] = acc0;
  *(float4*)&Zp_s[wave][1][4 * lane] = acc1;
  *(float4*)&Zp_s[wave][2][4 * lane] = acc2;
  *(float4*)&Zp_s[wave][3][4 * lane] = acc3;
  if (lane == 0) {
    mw_s[wave][0] = m0; mw_s[wave][1] = m1; mw_s[wave][2] = m2; mw_s[wave][3] = m3;
    sumw_s[wave][0] = u0; sumw_s[wave][1] = u1; sumw_s[wave][2] = u2; sumw_s[wave][3] = u3;
  }
  __syncthreads();

  // merge 4 wave-partials (every thread computes the small merge redundantly)
  float M0 = fmaxf(fmaxf(mw_s[0][0], mw_s[1][0]), fmaxf(mw_s[2][0], mw_s[3][0]));
  float M1 = fmaxf(fmaxf(mw_s[0][1], mw_s[1][1]), fmaxf(mw_s[2][1], mw_s[3][1]));
  float M2 = fmaxf(fmaxf(mw_s[0][2], mw_s[1][2]), fmaxf(mw_s[2][2], mw_s[3][2]));
  float M3 = fmaxf(fmaxf(mw_s[0][3], mw_s[1][3]), fmaxf(mw_s[2][3], mw_s[3][3]));
  float f00 = __expf(mw_s[0][0]-M0), f10 = __expf(mw_s[1][0]-M0),
        f20 = __expf(mw_s[2][0]-M0), f30 = __expf(mw_s[3][0]-M0);
  float f01 = __expf(mw_s[0][1]-M1), f11 = __expf(mw_s[1][1]-M1),
        f21 = __expf(mw_s[2][1]-M1), f31 = __expf(mw_s[3][1]-M1);
  float f02 = __expf(mw_s[0][2]-M2), f12 = __expf(mw_s[1][2]-M2),
        f22 = __expf(mw_s[2][2]-M2), f32 = __expf(mw_s[3][2]-M2);
  float f03 = __expf(mw_s[0][3]-M3), f13 = __expf(mw_s[1][3]-M3),
        f23 = __expf(mw_s[2][3]-M3), f33 = __expf(mw_s[3][3]-M3);
  float inv0 = 1.0f / (f00*sumw_s[0][0] + f10*sumw_s[1][0] + f20*sumw_s[2][0] + f30*sumw_s[3][0]);
  float inv1 = 1.0f / (f01*sumw_s[0][1] + f11*sumw_s[1][1] + f21*sumw_s[2][1] + f31*sumw_s[3][1]);
  float inv2 = 1.0f / (f02*sumw_s[0][2] + f12*sumw_s[1][2] + f22*sumw_s[2][2] + f32*sumw_s[3][2]);
  float inv3 = 1.0f / (f03*sumw_s[0][3] + f13*sumw_s[1][3] + f23*sumw_s[2][3] + f33*sumw_s[3][3]);

  size_t zb = (size_t)b * (H * E);
  Zws[zb + 0*E + t] = (f00*Zp_s[0][0][t] + f10*Zp_s[1][0][t] + f20*Zp_s[2][0][t] + f30*Zp_s[3][0][t]) * inv0;
  Zws[zb + 1*E + t] = (f01*Zp_s[0][1][t] + f11*Zp_s[1][1][t] + f21*Zp_s[2][1][t] + f31*Zp_s[3][1][t]) * inv1;
  Zws[zb + 2*E + t] = (f02*Zp_s[0][2][t] + f12*Zp_s[1][2][t] + f22*Zp_s[2][2][t] + f32*Zp_s[3][2][t]) * inv2;
  Zws[zb + 3*E + t] = (f03*Zp_s[0][3][t] + f13*Zp_s[1][3][t] + f23*Zp_s[2][3][t] + f33*Zp_s[3][3][t]) * inv3;

  if (t < L) {
    float v = 0.f;
    if (t < n)
      v = 0.25f * (__expf(s_s[0][t] - M0) * inv0 + __expf(s_s[1][t] - M1) * inv1 +
                   __expf(s_s[2][t] - M2) * inv2 + __expf(s_s[3][t] - M3) * inv3);
    attnw[(size_t)b * L + t] = v;
  }
}

// ---------------------------------------------------------------------------
// Kernel 3: ctx = Wv_h @ Z_h + bv ; out-proj + residual + LayerNorm.
// 4 batches per block, 256 blocks.
// ---------------------------------------------------------------------------
__global__ __launch_bounds__(256) void out_kernel(
    const float* __restrict__ scene, const float* __restrict__ Zws,
    const float* __restrict__ ipw, const float* __restrict__ ipb,
    const float* __restrict__ opw, const float* __restrict__ opb,
    const float* __restrict__ gamma, const float* __restrict__ beta,
    float* __restrict__ fused)
{
  int b0 = blockIdx.x * 4;
  int t = threadIdx.x;
  int wave = t >> 6, lane = t & 63;

  __shared__ float Z_s[4][H * E];
  __shared__ float ctx_s[4][E];
  __shared__ float x_s[4][E];

  for (int i = t; i < 4 * H * E; i += 256)
    ((float*)Z_s)[i] = Zws[(size_t)b0 * (H * E) + i];
  __syncthreads();

  {
    int h = t >> 6;
    const float* wvrow = ipw + (size_t)2 * E * E + (size_t)t * E;
    float base = ipb[2 * E + t];
    float a0 = base, a1 = base, a2 = base, a3 = base;
#pragma unroll 8
    for (int j = 0; j < E; j += 4) {
      float4 w4 = *(const float4*)(wvrow + j);
      const float* z0 = &Z_s[0][h * E + j];
      const float* z1 = &Z_s[1][h * E + j];
      const float* z2 = &Z_s[2][h * E + j];
      const float* z3 = &Z_s[3][h * E + j];
      a0 += z0[0]*w4.x + z0[1]*w4.y + z0[2]*w4.z + z0[3]*w4.w;
      a1 += z1[0]*w4.x + z1[1]*w4.y + z1[2]*w4.z + z1[3]*w4.w;
      a2 += z2[0]*w4.x + z2[1]*w4.y + z2[2]*w4.z + z2[3]*w4.w;
      a3 += z3[0]*w4.x + z3[1]*w4.y + z3[2]*w4.z + z3[3]*w4.w;
    }
    ctx_s[0][t] = a0; ctx_s[1][t] = a1; ctx_s[2][t] = a2; ctx_s[3][t] = a3;
  }
  __syncthreads();

  {
    const float* wrow = opw + (size_t)t * E;
    float base = opb[t];
    float a0 = base, a1 = base, a2 = base, a3 = base;
#pragma unroll 8
    for (int j = 0; j < E; j += 4) {
      float4 w4 = *(const float4*)(wrow + j);
      a0 += ctx_s[0][j]*w4.x + ctx_s[0][j+1]*w4.y + ctx_s[0][j+2]*w4.z + ctx_s[0][j+3]*w4.w;
      a1 += ctx_s[1][j]*w4.x + ctx_s[1][j+1]*w4.y + ctx_s[1][j+2]*w4.z + ctx_s[1][j+3]*w4.w;
      a2 += ctx_s[2][j]*w4.x + ctx_s[2][j+1]*w4.y + ctx_s[2][j+2]*w4.z + ctx_s[2][j+3]*w4.w;
      a3 += ctx_s[3][j]*w4.x + ctx_s[3][j+1]*w4.y + ctx_s[3][j+2]*w4.z + ctx_s[3][j+3]*w4.w;
    }
    x_s[0][t] = a0 + scene[(size_t)(b0 + 0) * E + t];
    x_s[1][t] = a1 + scene[(size_t)(b0 + 1) * E + t];
    x_s[2][t] = a2 + scene[(size_t)(b0 + 2) * E + t];
    x_s[3][t] = a3 + scene[(size_t)(b0 + 3) * E + t];
  }
  __syncthreads();

  {
    float v0 = x_s[wave][lane], v1 = x_s[wave][lane + 64],
          v2 = x_s[wave][lane + 128], v3 = x_s[wave][lane + 192];
    float s1 = v0 + v1 + v2 + v3;
#pragma unroll
    for (int o = 32; o; o >>= 1) s1 += __shfl_xor(s1, o);
    float mu = s1 * (1.0f / E);
    float d0 = v0 - mu, d1 = v1 - mu, d2 = v2 - mu, d3 = v3 - mu;
    float s2 = d0*d0 + d1*d1 + d2*d2 + d3*d3;
#pragma unroll
    for (int o = 32; o; o >>= 1) s2 += __shfl_xor(s2, o);
    float inv = 1.0f / sqrtf(s2 * (1.0f / E) + 1e-5f);
    size_t base = (size_t)(b0 + wave) * E;
    fused[base + lane      ] = d0 * inv * gamma[lane      ] + beta[lane      ];
    fused[base + lane +  64] = d1 * inv * gamma[lane +  64] + beta[lane +  64];
    fused[base + lane + 128] = d2 * inv * gamma[lane + 128] + beta[lane + 128];
    fused[base + lane + 192] = d3 * inv * gamma[lane + 192] + beta[lane + 192];
  }
}

// ---------------------------------------------------------------------------
extern "C" void kernel_launch(void* const* d_in, const int* in_sizes, int n_in,
                              void* d_out, int out_size, void* d_ws, size_t ws_size,
                              hipStream_t stream) {
  const float* scene = (const float*)d_in[0];
  const float* face  = (const float*)d_in[1];
  const float* obj   = (const float*)d_in[2];
  const int*   fb    = (const int*)d_in[3];
  const int*   ob    = (const int*)d_in[4];
  const float* ipw   = (const float*)d_in[5];
  const float* ipb   = (const float*)d_in[6];
  const float* opw   = (const float*)d_in[7];
  const float* opb   = (const float*)d_in[8];
  const float* gam   = (const float*)d_in[9];
  const float* bet   = (const float*)d_in[10];

  float* fused = (float*)d_out;
  float* attnw = fused + (size_t)B * E;

  // ws layout: starts (16KB) | Y (4MB) | sb (16KB) | Z (4MB)
  int* start_f = (int*)d_ws;
  int* start_o = start_f + (B + 1);
  float* Yws  = (float*)((char*)d_ws + (16 << 10));
  float* sbws = Yws + (size_t)B * H * E;
  float* Zws  = sbws + (size_t)B * H;

  qy_kernel<<<B / 4, 256, 0, stream>>>(scene, ipw, ipb, fb, ob, start_f, start_o, Yws, sbws);
  stream_kernel<<<B, 256, 0, stream>>>(face, obj, Yws, sbws, start_f, start_o, Zws, attnw);
  out_kernel<<<B / 4, 256, 0, stream>>>(scene, Zws, ipw, ipb, opw, opb, gam, bet, fused);
}